// Round 7
// baseline (262.270 us; speedup 1.0000x reference)
//
#include <hip/hip_runtime.h>
#include <hip/hip_bf16.h>
#include <hip/hip_cooperative_groups.h>
#include <math.h>

namespace cg = cooperative_groups;

#define NROWS 8192
#define DIM   2048
#define NC    256
#define ALPHA_C 7.18f

typedef float  f32x4  __attribute__((ext_vector_type(4)));
typedef __bf16 bf16x8 __attribute__((ext_vector_type(8)));

// ---------------- workspace layout (bytes) ----------------
// A_swz : 32 MiB  bf16 [512 mt][64 kk][64 lane][8]
// B_swz :  1 MiB  bf16 [16 nt][64 kk][64 lane][8]
// perm  : 32 KiB  int[8192]
// zero region (35 KiB, memset): gctr[256] | mn2[256] | scal | dsum[8192]
// then: counts[256] | base[256] | onorm2[8192] | rn[8192]
#define OFF_A      (size_t)0
#define OFF_B      ((size_t)32 << 20)
#define OFF_PERM   ((size_t)33 << 20)
#define OFF_Z      (OFF_PERM + 32768)
#define OFF_GCTR   (OFF_Z)
#define OFF_MN2    (OFF_Z + 1024)
#define OFF_SCAL   (OFF_Z + 2048)
#define OFF_DSUM   (OFF_Z + 3072)
#define ZSIZE      (3072 + 32768)
#define OFF_CNT    (OFF_Z + ZSIZE)
#define OFF_BASE   (OFF_CNT + 1024)
#define OFF_ON2    (OFF_BASE + 1024)
#define OFF_RN     (OFF_ON2 + 32768)
// scal: [0]=sum_resid(atomic) [1]=num_instances [3]=loss_sum(atomic)

__device__ __forceinline__ float wave_red_sum(float v) {
#pragma unroll
  for (int off = 32; off > 0; off >>= 1) v += __shfl_xor(v, off, 64);
  return v;
}

// ---------------- hist + scan + counts + num_instances (1 block) ----------------
__global__ __launch_bounds__(256) void k_prep(const int* __restrict__ clu,
                                              float* __restrict__ counts,
                                              int* __restrict__ base,
                                              float* scal) {
  __shared__ int h[NC];
  __shared__ int pre[NC];
  __shared__ float part[4];
  int tid = threadIdx.x;
  h[tid] = 0;
  __syncthreads();
  const int4* cl4 = (const int4*)clu;
#pragma unroll
  for (int s = 0; s < 8; ++s) {
    int4 v = cl4[s * 256 + tid];
    atomicAdd(&h[v.x], 1); atomicAdd(&h[v.y], 1);
    atomicAdd(&h[v.z], 1); atomicAdd(&h[v.w], 1);
  }
  __syncthreads();
  int c = h[tid];
  counts[tid] = (float)c;
  pre[tid] = c;
  __syncthreads();
  for (int off = 1; off < NC; off <<= 1) {
    int v = (tid >= off) ? pre[tid - off] : 0;
    __syncthreads();
    pre[tid] += v;
    __syncthreads();
  }
  base[tid] = pre[tid] - c;  // exclusive prefix
  float v = (c >= 4) ? (float)c : 0.0f;
  v = wave_red_sum(v);
  if ((tid & 63) == 0) part[tid >> 6] = v;
  __syncthreads();
  if (tid == 0) scal[1] = part[0] + part[1] + part[2] + part[3];
}

// ---------------- build permutation grouping rows by cluster ----------------
__global__ __launch_bounds__(256) void k_perm(const int* __restrict__ clu,
                                              const int* __restrict__ base,
                                              int* __restrict__ gctr,
                                              int* __restrict__ perm) {
  int i = blockIdx.x * 256 + threadIdx.x;
  int c = clu[i];
  int r = atomicAdd(&gctr[c], 1);
  perm[base[c] + r] = i;
}

// ---------------- outputs -> A_swz + onorm2, one block per 16-row M-tile ----------------
__global__ __launch_bounds__(256) void k_conv(const float* __restrict__ out,
                                              bf16x8* __restrict__ A,
                                              float* __restrict__ onorm2) {
  __shared__ float lsum[256];
  int mt = blockIdx.x, tid = threadIdx.x;
  int r = tid & 15;
  const float* rowp = out + ((size_t)mt * 16 + r) * DIM;
  bf16x8* At = A + (size_t)mt * 4096;
  float acc = 0.f;
#pragma unroll 4
  for (int s = 0; s < 16; ++s) {
    int q = s * 256 + tid;
    int kk = q >> 6, lane = q & 63;
    int d = kk * 32 + (lane >> 4) * 8;
    const f32x4* src = (const f32x4*)(rowp + d);
    f32x4 v0 = src[0], v1 = src[1];
    bf16x8 b;
#pragma unroll
    for (int j = 0; j < 4; ++j) { float f = v0[j]; acc += f * f; b[j] = (__bf16)f; }
#pragma unroll
    for (int j = 0; j < 4; ++j) { float f = v1[j]; acc += f * f; b[4 + j] = (__bf16)f; }
    At[q] = b;
  }
  lsum[tid] = acc;
  __syncthreads();
  if (tid < 16) {
    float s = 0.f;
#pragma unroll
    for (int k = 0; k < 16; ++k) s += lsum[tid + 16 * k];
    onorm2[mt * 16 + tid] = s;
  }
}

// ---------------- means via gather-reduce over sorted rows ----------------
__global__ __launch_bounds__(256) void k_msum(const float* __restrict__ out,
                                              const int* __restrict__ perm,
                                              const int* __restrict__ base,
                                              const float* __restrict__ counts,
                                              __bf16* __restrict__ B,
                                              float* __restrict__ mn2) {
  __shared__ int pr[64];
  __shared__ float part[4];
  int bid = blockIdx.x;
  int c = bid >> 3, sl = bid & 7;
  int tid = threadIdx.x;
  int col = sl * 256 + tid;
  int cnt = (int)counts[c];
  int b0 = base[c];
  float acc = 0.f;
  for (int r0 = 0; r0 < cnt; r0 += 64) {
    int lim = min(64, cnt - r0);
    if (tid < lim) pr[tid] = perm[b0 + r0 + tid];
    __syncthreads();
    for (int r = 0; r < lim; ++r) acc += out[(size_t)pr[r] * DIM + col];
    __syncthreads();
  }
  float mean = acc / fmaxf((float)cnt, 1.f);
  int nt = c >> 4, kk = col >> 5, lane = ((col >> 3) & 3) * 16 + (c & 15), j = col & 7;
  B[(((size_t)nt * 64 + kk) * 64 + lane) * 8 + j] = (__bf16)mean;
  float s = mean * mean;
  s = wave_red_sum(s);
  if ((tid & 63) == 0) part[tid >> 6] = s;
  __syncthreads();
  if (tid == 0) atomicAdd(&mn2[c], part[0] + part[1] + part[2] + part[3]);
}

// ---------------- fused GEMM + resid + stdev + denom + loss (cooperative) ----------------
// 256 blocks = 64 M-blocks x 4 N-blocks; dot tile stays in registers.
__global__ __launch_bounds__(256) void k_fused(const bf16x8* __restrict__ A,
                                               const bf16x8* __restrict__ B,
                                               const int* __restrict__ clu,
                                               const float* __restrict__ counts,
                                               const float* __restrict__ on2v,
                                               const float* __restrict__ mn2,
                                               float* __restrict__ rn,
                                               float* __restrict__ dsum,
                                               float* scal,
                                               float* outp) {
  __shared__ float part[4];
  cg::grid_group grid = cg::this_grid();
  int bid = blockIdx.x;
  int wg = (bid & 7) * 32 + (bid >> 3);   // bijective XCD swizzle: 256 = 8 x 32
  int bm = wg >> 2, bn = wg & 3;
  int w = threadIdx.x >> 6, l = threadIdx.x & 63;
  int mt0 = bm * 8 + w * 2;
  int nt0 = bn * 4;
  const bf16x8* Ap = A + (size_t)mt0 * 64 * 64 + l;
  const bf16x8* Bp = B + (size_t)nt0 * 64 * 64 + l;
  f32x4 acc[2][4] = {};
  for (int kk = 0; kk < 64; ++kk) {
    bf16x8 a0 = Ap[kk * 64];
    bf16x8 a1 = Ap[4096 + kk * 64];
    bf16x8 b0 = Bp[kk * 64];
    bf16x8 b1 = Bp[4096 + kk * 64];
    bf16x8 b2 = Bp[8192 + kk * 64];
    bf16x8 b3 = Bp[12288 + kk * 64];
    acc[0][0] = __builtin_amdgcn_mfma_f32_16x16x32_bf16(a0, b0, acc[0][0], 0, 0, 0);
    acc[0][1] = __builtin_amdgcn_mfma_f32_16x16x32_bf16(a0, b1, acc[0][1], 0, 0, 0);
    acc[0][2] = __builtin_amdgcn_mfma_f32_16x16x32_bf16(a0, b2, acc[0][2], 0, 0, 0);
    acc[0][3] = __builtin_amdgcn_mfma_f32_16x16x32_bf16(a0, b3, acc[0][3], 0, 0, 0);
    acc[1][0] = __builtin_amdgcn_mfma_f32_16x16x32_bf16(a1, b0, acc[1][0], 0, 0, 0);
    acc[1][1] = __builtin_amdgcn_mfma_f32_16x16x32_bf16(a1, b1, acc[1][1], 0, 0, 0);
    acc[1][2] = __builtin_amdgcn_mfma_f32_16x16x32_bf16(a1, b2, acc[1][2], 0, 0, 0);
    acc[1][3] = __builtin_amdgcn_mfma_f32_16x16x32_bf16(a1, b3, acc[1][3], 0, 0, 0);
  }
  // C/D layout (m89-verified): row = r0 + m*16 + reg, col = cb + n*16
  int r0 = bm * 128 + w * 32 + (l >> 4) * 4;
  int cb = bn * 64 + (l & 15);

  // ---- phase A: resid norms (thread holding (i, clu[i]) computes rn[i]) ----
  int ciArr[8]; float on2Arr[8];
  float rsum = 0.f;
#pragma unroll
  for (int m = 0; m < 2; ++m)
#pragma unroll
    for (int reg = 0; reg < 4; ++reg) {
      int idx = m * 4 + reg;
      int i = r0 + m * 16 + reg;
      int ci = clu[i];
      float o2 = on2v[i];
      ciArr[idx] = ci; on2Arr[idx] = o2;
#pragma unroll
      for (int n = 0; n < 4; ++n) {
        int c = cb + n * 16;
        if (c == ci) {
          float v = acc[m][n][reg];
          float rnv = sqrtf(fmaxf(o2 - 2.f * v + mn2[ci], 0.f));
          rn[i] = rnv;
          if (counts[ci] >= 4.f) rsum += rnv;
        }
      }
    }
  rsum = wave_red_sum(rsum);
  if (l == 0) part[w] = rsum;
  __syncthreads();
  if (threadIdx.x == 0) atomicAdd(&scal[0], part[0] + part[1] + part[2] + part[3]);
  grid.sync();

  // ---- phase B: denom partials (per-row sum over this block's 64 cols) ----
  float s0 = scal[0], s1 = scal[1];
  float cfac = -0.5f * s1 / (s0 * s0);   // = -0.5 / stdev
  float mnc[4], cnc[4];
#pragma unroll
  for (int n = 0; n < 4; ++n) { int c = cb + n * 16; mnc[n] = mn2[c]; cnc[n] = counts[c]; }
#pragma unroll
  for (int m = 0; m < 2; ++m)
#pragma unroll
    for (int reg = 0; reg < 4; ++reg) {
      int idx = m * 4 + reg;
      int i = r0 + m * 16 + reg;
      int ci = ciArr[idx];
      float o2 = on2Arr[idx];
      float p = 0.f;
#pragma unroll
      for (int n = 0; n < 4; ++n) {
        int c = cb + n * 16;
        float v = acc[m][n][reg];
        float dist = sqrtf(fmaxf(o2 - 2.f * v + mnc[n], 0.f));
        float e = __expf(cfac * dist);
        p += ((cnc[n] >= 4.f) && (c != ci)) ? e : 0.f;
      }
      // reduce across the 16 lanes (l&15 = 0..15) holding this row
#pragma unroll
      for (int off = 1; off < 16; off <<= 1) p += __shfl_xor(p, off, 64);
      if ((l & 15) == 0) atomicAdd(&dsum[i], p);
    }
  grid.sync();

  // ---- phase C: per-row loss ----
  float lv = 0.f;
  int tid = threadIdx.x;
  if (tid < 32) {
    int i = blockIdx.x * 32 + tid;
    int ci = clu[i];
    if (counts[ci] >= 4.f)
      lv = __logf(dsum[i]) - (cfac * rn[i] - ALPHA_C);
  }
  lv = wave_red_sum(lv);
  if (l == 0) part[w] = lv;
  __syncthreads();
  if (tid == 0) atomicAdd(&scal[3], part[0] + part[1] + part[2] + part[3]);
  grid.sync();

  if (blockIdx.x == 0 && tid == 0) outp[0] = scal[3] / scal[1];
}

extern "C" void kernel_launch(void* const* d_in, const int* in_sizes, int n_in,
                              void* d_out, int out_size, void* d_ws, size_t ws_size,
                              hipStream_t stream) {
  const float* outputs = (const float*)d_in[0];
  const int* clusters = (const int*)d_in[1];
  float* outp = (float*)d_out;
  char* ws = (char*)d_ws;

  bf16x8* A      = (bf16x8*)(ws + OFF_A);
  bf16x8* B      = (bf16x8*)(ws + OFF_B);
  int*    perm   = (int*)(ws + OFF_PERM);
  int*    gctr   = (int*)(ws + OFF_GCTR);
  float*  mn2    = (float*)(ws + OFF_MN2);
  float*  scal   = (float*)(ws + OFF_SCAL);
  float*  dsum   = (float*)(ws + OFF_DSUM);
  float*  counts = (float*)(ws + OFF_CNT);
  int*    base   = (int*)(ws + OFF_BASE);
  float*  on2    = (float*)(ws + OFF_ON2);
  float*  rn     = (float*)(ws + OFF_RN);

  hipMemsetAsync(ws + OFF_Z, 0, ZSIZE, stream);  // gctr, mn2, scal, dsum
  k_prep<<<1, 256, 0, stream>>>(clusters, counts, base, scal);
  k_perm<<<NROWS / 256, 256, 0, stream>>>(clusters, base, gctr, perm);
  k_conv<<<NROWS / 16, 256, 0, stream>>>(outputs, A, on2);
  k_msum<<<NC * 8, 256, 0, stream>>>(outputs, perm, base, counts, (__bf16*)B, mn2);

  void* kargs[] = {(void*)&A, (void*)&B, (void*)&clusters, (void*)&counts,
                   (void*)&on2, (void*)&mn2, (void*)&rn, (void*)&dsum,
                   (void*)&scal, (void*)&outp};
  hipLaunchCooperativeKernel((const void*)k_fused, dim3(256), dim3(256), kargs, 0, stream);
}

// Round 13
// 172.225 us; speedup vs baseline: 1.5228x; 1.5228x over previous
//
#include <hip/hip_runtime.h>
#include <hip/hip_bf16.h>
#include <math.h>

#define NROWS 8192
#define DIM   2048
#define NC    256
#define ALPHA_C 7.18f

typedef float  f32x4  __attribute__((ext_vector_type(4)));
typedef __bf16 bf16x8 __attribute__((ext_vector_type(8)));

// ---------------- workspace layout (bytes) ----------------
#define OFF_A      (size_t)0
#define OFF_DOT    ((size_t)32 << 20)
#define OFF_B      ((size_t)40 << 20)
#define OFF_PERM   ((size_t)41 << 20)
#define OFF_MISC   (OFF_PERM + 32768)
#define OFF_GCTR   (OFF_MISC)
#define OFF_MN2    (OFF_MISC + 1024)
#define OFF_SCAL   (OFF_MISC + 2048)
#define OFF_HIST   (OFF_MISC + 3072)
#define OFF_CNT    (OFF_MISC + 4096)
#define OFF_BASE   (OFF_MISC + 5120)
#define OFF_ON2    (OFF_MISC + 6144)
// scal: [0]=sum_resid(atomic) [1]=num_instances [3]=loss_sum(atomic)

__device__ __forceinline__ float wave_red_sum(float v) {
#pragma unroll
  for (int off = 32; off > 0; off >>= 1) v += __shfl_xor(v, off, 64);
  return v;
}

// ---------------- histogram of cluster ids (32 blocks) ----------------
__global__ __launch_bounds__(256) void k_hist(const int* __restrict__ clu,
                                              int* __restrict__ hist) {
  __shared__ int h[NC];
  int tid = threadIdx.x;
  h[tid] = 0;
  __syncthreads();
  atomicAdd(&h[clu[blockIdx.x * 256 + tid]], 1);
  __syncthreads();
  if (h[tid]) atomicAdd(&hist[tid], h[tid]);
}

// ---------------- prefix + counts + num_instances (1 tiny block) ----------------
__global__ __launch_bounds__(256) void k_scan(const int* __restrict__ hist,
                                              float* __restrict__ counts,
                                              int* __restrict__ base,
                                              float* scal) {
  __shared__ int pre[NC];
  __shared__ float part[4];
  int tid = threadIdx.x;
  int c = hist[tid];
  counts[tid] = (float)c;
  pre[tid] = c;
  __syncthreads();
  for (int off = 1; off < NC; off <<= 1) {
    int v = (tid >= off) ? pre[tid - off] : 0;
    __syncthreads();
    pre[tid] += v;
    __syncthreads();
  }
  base[tid] = pre[tid] - c;  // exclusive prefix
  float v = (c >= 4) ? (float)c : 0.0f;
  v = wave_red_sum(v);
  if ((tid & 63) == 0) part[tid >> 6] = v;
  __syncthreads();
  if (tid == 0) scal[1] = part[0] + part[1] + part[2] + part[3];
}

// ---------------- build permutation grouping rows by cluster ----------------
__global__ __launch_bounds__(256) void k_perm(const int* __restrict__ clu,
                                              const int* __restrict__ base,
                                              int* __restrict__ gctr,
                                              int* __restrict__ perm) {
  int i = blockIdx.x * 256 + threadIdx.x;
  int c = clu[i];
  int r = atomicAdd(&gctr[c], 1);
  perm[base[c] + r] = i;
}

// ---------------- outputs -> A_swz + onorm2, one block per 16-row M-tile ----------------
__global__ __launch_bounds__(256) void k_conv(const float* __restrict__ out,
                                              bf16x8* __restrict__ A,
                                              float* __restrict__ onorm2) {
  __shared__ float lsum[256];
  int mt = blockIdx.x, tid = threadIdx.x;
  int r = tid & 15;
  const float* rowp = out + ((size_t)mt * 16 + r) * DIM;
  bf16x8* At = A + (size_t)mt * 4096;
  float acc = 0.f;
#pragma unroll 4
  for (int s = 0; s < 16; ++s) {
    int q = s * 256 + tid;
    int kk = q >> 6, lane = q & 63;
    int d = kk * 32 + (lane >> 4) * 8;
    const f32x4* src = (const f32x4*)(rowp + d);
    f32x4 v0 = src[0], v1 = src[1];
    bf16x8 b;
#pragma unroll
    for (int j = 0; j < 4; ++j) { float f = v0[j]; acc += f * f; b[j] = (__bf16)f; }
#pragma unroll
    for (int j = 0; j < 4; ++j) { float f = v1[j]; acc += f * f; b[4 + j] = (__bf16)f; }
    At[q] = b;
  }
  lsum[tid] = acc;
  __syncthreads();
  if (tid < 16) {
    float s = 0.f;
#pragma unroll
    for (int k = 0; k < 16; ++k) s += lsum[tid + 16 * k];
    onorm2[mt * 16 + tid] = s;
  }
}

// ---------------- means via gather-reduce over sorted rows ----------------
__global__ __launch_bounds__(256) void k_msum(const float* __restrict__ out,
                                              const int* __restrict__ perm,
                                              const int* __restrict__ base,
                                              const float* __restrict__ counts,
                                              __bf16* __restrict__ B,
                                              float* __restrict__ mn2) {
  __shared__ int pr[64];
  __shared__ float part[4];
  int bid = blockIdx.x;
  int c = bid >> 3, sl = bid & 7;
  int tid = threadIdx.x;
  int col = sl * 256 + tid;
  int cnt = (int)counts[c];
  int b0 = base[c];
  float acc = 0.f;
  for (int r0 = 0; r0 < cnt; r0 += 64) {
    int lim = min(64, cnt - r0);
    if (tid < lim) pr[tid] = perm[b0 + r0 + tid];
    __syncthreads();
    for (int r = 0; r < lim; ++r) acc += out[(size_t)pr[r] * DIM + col];
    __syncthreads();
  }
  float mean = acc / fmaxf((float)cnt, 1.f);
  int nt = c >> 4, kk = col >> 5, lane = ((col >> 3) & 3) * 16 + (c & 15), j = col & 7;
  B[(((size_t)nt * 64 + kk) * 64 + lane) * 8 + j] = (__bf16)mean;
  float s = mean * mean;
  s = wave_red_sum(s);
  if ((tid & 63) == 0) part[tid >> 6] = s;
  __syncthreads();
  if (tid == 0) atomicAdd(&mn2[c], part[0] + part[1] + part[2] + part[3]);
}

// ---------------- GEMM + resid-norm epilogue: 512 blocks (2/CU), 64x64 tile ----------------
__global__ __launch_bounds__(256) void k_gemm(const bf16x8* __restrict__ A,
                                              const bf16x8* __restrict__ B,
                                              const int* __restrict__ clu,
                                              const float* __restrict__ counts,
                                              const float* __restrict__ on2v,
                                              const float* __restrict__ mn2,
                                              float* __restrict__ dot,
                                              float* scal) {
  __shared__ float part[4];
  int bid = blockIdx.x;
  int wg = (bid & 7) * 64 + (bid >> 3);   // bijective: 512 = 8 XCD x 64
  int bm = wg >> 2, bn = wg & 3;          // bm 0..127, bn 0..3
  int w = threadIdx.x >> 6, l = threadIdx.x & 63;
  int mt = bm * 4 + w;
  int nt0 = bn * 4;
  const bf16x8* Ap = A + (size_t)mt * 4096 + l;
  const bf16x8* Bp = B + (size_t)nt0 * 4096 + l;
  f32x4 acc[4] = {};
#pragma unroll 2
  for (int kk = 0; kk < 64; ++kk) {
    bf16x8 a0 = Ap[kk * 64];
    bf16x8 b0 = Bp[kk * 64];
    bf16x8 b1 = Bp[4096 + kk * 64];
    bf16x8 b2 = Bp[8192 + kk * 64];
    bf16x8 b3 = Bp[12288 + kk * 64];
    acc[0] = __builtin_amdgcn_mfma_f32_16x16x32_bf16(a0, b0, acc[0], 0, 0, 0);
    acc[1] = __builtin_amdgcn_mfma_f32_16x16x32_bf16(a0, b1, acc[1], 0, 0, 0);
    acc[2] = __builtin_amdgcn_mfma_f32_16x16x32_bf16(a0, b2, acc[2], 0, 0, 0);
    acc[3] = __builtin_amdgcn_mfma_f32_16x16x32_bf16(a0, b3, acc[3], 0, 0, 0);
  }
  // C/D layout (m89-verified): col = l&15, row = (l>>4)*4 + reg
  int r0 = bm * 64 + w * 16 + (l >> 4) * 4;
  int cb = bn * 64 + (l & 15);
#pragma unroll
  for (int reg = 0; reg < 4; ++reg) {
    float* dst = dot + (size_t)(r0 + reg) * NC + cb;
    dst[0]  = acc[0][reg];
    dst[16] = acc[1][reg];
    dst[32] = acc[2][reg];
    dst[48] = acc[3][reg];
  }
  // ---- resid-norm epilogue (phase-A logic, HW-validated round 7) ----
  float rsum = 0.f;
#pragma unroll
  for (int reg = 0; reg < 4; ++reg) {
    int i = r0 + reg;
    int ci = clu[i];
#pragma unroll
    for (int n = 0; n < 4; ++n) {
      int c = cb + n * 16;
      if (c == ci && counts[ci] >= 4.0f) {
        rsum += sqrtf(fmaxf(on2v[i] - 2.f * acc[n][reg] + mn2[ci], 0.f));
      }
    }
  }
  rsum = wave_red_sum(rsum);
  if (l == 0) part[w] = rsum;
  __syncthreads();
  if (threadIdx.x == 0) {
    float t = part[0] + part[1] + part[2] + part[3];
    if (t != 0.f) atomicAdd(&scal[0], t);
  }
}

// ---------------- denom + loss (stdev folded in): 256 blocks x 32 rows ----------------
__global__ __launch_bounds__(256) void k_denom(const float* __restrict__ dot,
                                               const int* __restrict__ clu,
                                               const float* __restrict__ on2v,
                                               const float* __restrict__ mn2,
                                               const float* __restrict__ counts,
                                               float* scal) {
  __shared__ float part[4];
  int w = threadIdx.x >> 6, l = threadIdx.x & 63;
  float s0 = scal[0], s1 = scal[1];
  float cfac = -0.5f * s1 / (s0 * s0);   // = -0.5 / stdev
  f32x4 mn = ((const f32x4*)mn2)[l];
  f32x4 cn = ((const f32x4*)counts)[l];
  float lsum = 0.f;
  int i0 = blockIdx.x * 32 + w * 8;
  for (int t = 0; t < 8; ++t) {
    int i = i0 + t;
    int ci = clu[i];
    float on2 = on2v[i];
    f32x4 dv = ((const f32x4*)(dot + (size_t)i * NC))[l];
    float dsum = 0.f;
#pragma unroll
    for (int j = 0; j < 4; ++j) {
      int cc = l * 4 + j;
      float dist = sqrtf(fmaxf(on2 - 2.f * dv[j] + mn[j], 0.f));
      float e = __expf(cfac * dist);
      dsum += ((cn[j] >= 4.0f) && (cc != ci)) ? e : 0.f;
    }
    dsum = wave_red_sum(dsum);
    if (l == 0 && counts[ci] >= 4.0f) {
      float dvi = dot[(size_t)i * NC + ci];
      float rn = sqrtf(fmaxf(on2 - 2.f * dvi + mn2[ci], 0.f));
      lsum += __logf(dsum) - (cfac * rn - ALPHA_C);
    }
  }
  lsum = wave_red_sum(lsum);
  if (l == 0) part[w] = lsum;
  __syncthreads();
  if (threadIdx.x == 0) atomicAdd(&scal[3], part[0] + part[1] + part[2] + part[3]);
}

__global__ void k_final(const float* scal, float* out) {
  out[0] = scal[3] / scal[1];
}

extern "C" void kernel_launch(void* const* d_in, const int* in_sizes, int n_in,
                              void* d_out, int out_size, void* d_ws, size_t ws_size,
                              hipStream_t stream) {
  const float* outputs = (const float*)d_in[0];
  const int* clusters = (const int*)d_in[1];
  float* out = (float*)d_out;
  char* ws = (char*)d_ws;

  bf16x8* A      = (bf16x8*)(ws + OFF_A);
  float*  dotb   = (float*)(ws + OFF_DOT);
  __bf16* B      = (__bf16*)(ws + OFF_B);
  int*    perm   = (int*)(ws + OFF_PERM);
  int*    gctr   = (int*)(ws + OFF_GCTR);
  float*  mn2    = (float*)(ws + OFF_MN2);
  float*  scal   = (float*)(ws + OFF_SCAL);
  int*    hist   = (int*)(ws + OFF_HIST);
  float*  counts = (float*)(ws + OFF_CNT);
  int*    base   = (int*)(ws + OFF_BASE);
  float*  on2    = (float*)(ws + OFF_ON2);

  hipMemsetAsync(ws + OFF_GCTR, 0, 4096, stream);  // gctr, mn2, scal, hist
  k_hist<<<NROWS / 256, 256, 0, stream>>>(clusters, hist);
  k_scan<<<1, 256, 0, stream>>>(hist, counts, base, scal);
  k_perm<<<NROWS / 256, 256, 0, stream>>>(clusters, base, gctr, perm);
  k_conv<<<NROWS / 16, 256, 0, stream>>>(outputs, A, on2);
  k_msum<<<NC * 8, 256, 0, stream>>>(outputs, perm, base, counts, B, mn2);
  k_gemm<<<512, 256, 0, stream>>>(A, (const bf16x8*)B, clusters, counts, on2, mn2, dotb, scal);
  k_denom<<<NROWS / 32, 256, 0, stream>>>(dotb, clusters, on2, mn2, counts, scal);
  k_final<<<1, 1, 0, stream>>>(scal, out);
}